// Round 5
// baseline (1588.452 us; speedup 1.0000x reference)
//
#include <hip/hip_runtime.h>
#include <hip/hip_bf16.h>

typedef unsigned short ushort_t;
using short8 = __attribute__((ext_vector_type(8))) short;
using f32x4  = __attribute__((ext_vector_type(4))) float;

#define DEVI __device__ __forceinline__

DEVI ushort_t f2bf(float f) {
    union { float f; unsigned u; } c; c.f = f;
    unsigned u = c.u;
    return (ushort_t)((u + 0x7FFF + ((u >> 16) & 1)) >> 16);
}

DEVI f32x4 mfma16(short8 a, short8 b, f32x4 c) {
    return __builtin_amdgcn_mfma_f32_16x16x32_bf16(a, b, c, 0, 0, 0);
}

DEVI void gld16(const void* g, void* l) {
    __builtin_amdgcn_global_load_lds(
        (const __attribute__((address_space(1))) unsigned int*)g,
        (__attribute__((address_space(3))) unsigned int*)l, 16, 0, 0);
}

// ---------------- constants ----------------
#define Bsz 16
#define Ntok 1024
#define Cdim 1152
#define Hn 16
#define Dh 72
#define Dp 96
#define INNER 4608
#define Mrows (Bsz * Ntok)   // 16384

// workspace offsets (bytes)
#define OFF_QKV_WT  ((size_t)0)
#define OFF_PROJ_WT ((size_t)7962624)
#define OFF_FC1_WT  ((size_t)10616832)
#define OFF_FC2_WT  ((size_t)21233664)
#define OFF_H       ((size_t)31850496)
#define OFF_ATT     ((size_t)69599232)
#define OFF_Q       ((size_t)107347968)
#define OFF_K       ((size_t)157679616)
#define OFF_VT      ((size_t)208011264)
// hidden (16384x4608 bf16 = 150994944 B) aliases OFF_Q..OFF_VT end (dead by then)
#define OFF_HIDDEN  OFF_Q

// ---------------- weight transpose + cast: W[K][N] f32 -> Wt[N][K] bf16 ----------------
__global__ __launch_bounds__(256) void transpose_cast(
    const float* __restrict__ W, ushort_t* __restrict__ Wt, int K, int N)
{
    __shared__ float t[64][65];
    const int n0 = blockIdx.x * 64;
    const int k0 = blockIdx.y * 64;
    #pragma unroll
    for (int j = 0; j < 4; ++j) {
        int idx = threadIdx.x + j * 256;
        int r = idx >> 4;       // k row 0..63
        int c4 = idx & 15;      // n group of 4
        float4 v = *(const float4*)&W[(size_t)(k0 + r) * N + n0 + c4 * 4];
        t[r][c4 * 4 + 0] = v.x; t[r][c4 * 4 + 1] = v.y;
        t[r][c4 * 4 + 2] = v.z; t[r][c4 * 4 + 3] = v.w;
    }
    __syncthreads();
    #pragma unroll
    for (int j = 0; j < 4; ++j) {
        int idx = threadIdx.x + j * 256;
        int rn = idx >> 4;      // n row 0..63
        int c4 = idx & 15;      // k group of 4
        ushort4 o;
        o.x = f2bf(t[c4 * 4 + 0][rn]);
        o.y = f2bf(t[c4 * 4 + 1][rn]);
        o.z = f2bf(t[c4 * 4 + 2][rn]);
        o.w = f2bf(t[c4 * 4 + 3][rn]);
        *(ushort4*)&Wt[(size_t)(n0 + rn) * K + k0 + c4 * 4] = o;
    }
}

// ---------------- LayerNorm: f32 row(1152) -> bf16 ----------------
__global__ __launch_bounds__(256) void ln_kernel(
    const float* __restrict__ x, const float* __restrict__ g,
    const float* __restrict__ b, ushort_t* __restrict__ out)
{
    const int row = blockIdx.x;
    const int tid = threadIdx.x;
    const int lane = tid & 63, wid = tid >> 6;
    const float* xr = x + (size_t)row * Cdim;

    float4 v0 = ((const float4*)xr)[tid];
    float4 v1 = {0, 0, 0, 0};
    if (tid < 32) v1 = ((const float4*)xr)[256 + tid];
    float s  = v0.x + v0.y + v0.z + v0.w + v1.x + v1.y + v1.z + v1.w;
    float s2 = v0.x*v0.x + v0.y*v0.y + v0.z*v0.z + v0.w*v0.w
             + v1.x*v1.x + v1.y*v1.y + v1.z*v1.z + v1.w*v1.w;
    #pragma unroll
    for (int off = 32; off >= 1; off >>= 1) {
        s  += __shfl_xor(s, off);
        s2 += __shfl_xor(s2, off);
    }
    __shared__ float red[8];
    if (lane == 0) { red[wid] = s; red[4 + wid] = s2; }
    __syncthreads();
    s  = red[0] + red[1] + red[2] + red[3];
    s2 = red[4] + red[5] + red[6] + red[7];
    const float mu = s * (1.0f / Cdim);
    const float var = s2 * (1.0f / Cdim) - mu * mu;
    const float rs = rsqrtf(var + 1e-6f);

    ushort_t* orow = out + (size_t)row * Cdim;
    {
        float4 g4 = ((const float4*)g)[tid];
        float4 b4 = ((const float4*)b)[tid];
        ushort4 o;
        o.x = f2bf((v0.x - mu) * rs * g4.x + b4.x);
        o.y = f2bf((v0.y - mu) * rs * g4.y + b4.y);
        o.z = f2bf((v0.z - mu) * rs * g4.z + b4.z);
        o.w = f2bf((v0.w - mu) * rs * g4.w + b4.w);
        ((ushort4*)orow)[tid] = o;
    }
    if (tid < 32) {
        float4 g4 = ((const float4*)g)[256 + tid];
        float4 b4 = ((const float4*)b)[256 + tid];
        ushort4 o;
        o.x = f2bf((v1.x - mu) * rs * g4.x + b4.x);
        o.y = f2bf((v1.y - mu) * rs * g4.y + b4.y);
        o.z = f2bf((v1.z - mu) * rs * g4.z + b4.z);
        o.w = f2bf((v1.w - mu) * rs * g4.w + b4.w);
        ((ushort4*)orow)[256 + tid] = o;
    }
}

// ---------------- GEMM: C[M,N] = A[M,K](bf16) @ Bt[N,K]^T(bf16), epilogues ----------------
enum { EPI_QKV = 0, EPI_PROJ = 1, EPI_FC1 = 2, EPI_FC2 = 3 };

template<int EPI, int N, int K>
__global__ __launch_bounds__(256) void gemm_bt(
    const ushort_t* __restrict__ A, const ushort_t* __restrict__ Bt,
    const float* __restrict__ bias, const float* __restrict__ resid,
    float* __restrict__ outf, ushort_t* __restrict__ outb,
    ushort_t* __restrict__ outq, ushort_t* __restrict__ outk, ushort_t* __restrict__ outv)
{
    __shared__ ushort_t As[128 * 32];
    __shared__ ushort_t Bs[128 * 32];
    const int tid = threadIdx.x;
    const int lane = tid & 63, wid = tid >> 6;

    // XCD-aware bijective swizzle on the linearized block id (nwg % 8 == 0 for all our grids)
    const int nwg = gridDim.x * gridDim.y;
    const int lid = blockIdx.y * gridDim.x + blockIdx.x;
    const int cpx = nwg >> 3;
    const int swz = (lid & 7) * cpx + (lid >> 3);
    const int m0 = (swz / gridDim.x) * 128;
    const int n0 = (swz % gridDim.x) * 128;
    const int fr = lane & 15, fq = lane >> 4;

    f32x4 acc[4][4] = {};

    const int srow = lane >> 2;          // 0..15 within 16-row chunk
    const int scol = (lane & 3) * 8;     // k element offset within 32
    const ushort_t* Ag = A + (size_t)m0 * K;
    const ushort_t* Bg = Bt + (size_t)n0 * K;

    for (int kk = 0; kk < K; kk += 32) {
        #pragma unroll
        for (int j = 0; j < 2; ++j) {
            const int crow = wid * 32 + j * 16;          // chunk base row
            gld16(Ag + (size_t)(crow + srow) * K + kk + scol, &As[crow * 32]);
            gld16(Bg + (size_t)(crow + srow) * K + kk + scol, &Bs[crow * 32]);
        }
        __syncthreads();
        short8 af[4], bfr[4];
        #pragma unroll
        for (int mi = 0; mi < 4; ++mi)
            af[mi] = *(const short8*)&As[((wid >> 1) * 64 + mi * 16 + fr) * 32 + fq * 8];
        #pragma unroll
        for (int ni = 0; ni < 4; ++ni)
            bfr[ni] = *(const short8*)&Bs[((wid & 1) * 64 + ni * 16 + fr) * 32 + fq * 8];
        __builtin_amdgcn_s_setprio(1);
        #pragma unroll
        for (int mi = 0; mi < 4; ++mi)
            #pragma unroll
            for (int ni = 0; ni < 4; ++ni)
                acc[mi][ni] = mfma16(af[mi], bfr[ni], acc[mi][ni]);
        __builtin_amdgcn_s_setprio(0);
        __syncthreads();
    }

    #pragma unroll
    for (int mi = 0; mi < 4; ++mi) {
        #pragma unroll
        for (int ni = 0; ni < 4; ++ni) {
            const int col = n0 + (wid & 1) * 64 + ni * 16 + fr;
            const int rbase = m0 + (wid >> 1) * 64 + mi * 16 + fq * 4;
            #pragma unroll
            for (int i = 0; i < 4; ++i) {
                const int r = rbase + i;
                float v = acc[mi][ni][i];
                if (EPI == EPI_QKV) {
                    v += bias[col];
                    const int which = col / Cdim;
                    const int rc = col % Cdim;
                    const int h = rc / Dh, d = rc % Dh;
                    const int b = r >> 10, n = r & 1023;
                    const size_t head = (size_t)(b * Hn + h);
                    if (which == 0)      outq[(head * Ntok + n) * Dp + d] = f2bf(v);
                    else if (which == 1) outk[(head * Ntok + n) * Dp + d] = f2bf(v);
                    else                 outv[(head * Dp + d) * Ntok + n] = f2bf(v);
                } else if (EPI == EPI_PROJ) {
                    v += bias[col] + resid[(size_t)r * N + col];
                    outf[(size_t)r * N + col] = v;
                } else if (EPI == EPI_FC1) {
                    v += bias[col];
                    v = 0.5f * v * (1.0f + erff(v * 0.70710678118f));
                    outb[(size_t)r * N + col] = f2bf(v);
                } else { // EPI_FC2
                    v += bias[col] + outf[(size_t)r * N + col];
                    outf[(size_t)r * N + col] = v;
                }
            }
        }
    }
}

// ---------------- flash attention: q,k (bh,n,96) bf16; vt (bh,96,n); out (b,n,1152) bf16 ----
// Per wave: 16 q-rows. Barrier-free (P-transpose LDS is wave-private).
// Defer-max (THR=8): o/lsum rescale only when the running max grows materially.
// Row-sum kept as per-lane partials; single shfl-reduce after the KV loop.
__global__ __launch_bounds__(256) void attn_kernel(
    const ushort_t* __restrict__ q, const ushort_t* __restrict__ k,
    const ushort_t* __restrict__ vt, ushort_t* __restrict__ out)
{
    const int tid = threadIdx.x;
    const int lane = tid & 63, wid = tid >> 6;
    const int bh = blockIdx.y;
    const int q0 = blockIdx.x * 64 + wid * 16;
    const int fr = lane & 15, fq = lane >> 4;
    const ushort_t* qh = q  + (size_t)bh * Ntok * Dp;
    const ushort_t* kh = k  + (size_t)bh * Ntok * Dp;
    const ushort_t* vh = vt + (size_t)bh * Dp * Ntok;

    short8 aq[3];
    #pragma unroll
    for (int ks = 0; ks < 3; ++ks)
        aq[ks] = *(const short8*)&qh[(size_t)(q0 + fr) * Dp + ks * 32 + fq * 8];

    f32x4 o[5] = {};
    float mrun[4], lsum[4];
    #pragma unroll
    for (int i = 0; i < 4; ++i) { mrun[i] = -1e30f; lsum[i] = 0.0f; }

    __shared__ ushort_t plds[4][16][32];
    const float scale = 0.117851130f;   // 72^-0.5

    for (int kv = 0; kv < Ntok; kv += 32) {
        f32x4 s0 = {}, s1 = {};
        __builtin_amdgcn_s_setprio(1);
        #pragma unroll
        for (int ks = 0; ks < 3; ++ks) {
            short8 b0 = *(const short8*)&kh[(size_t)(kv + fr) * Dp + ks * 32 + fq * 8];
            short8 b1 = *(const short8*)&kh[(size_t)(kv + 16 + fr) * Dp + ks * 32 + fq * 8];
            s0 = mfma16(aq[ks], b0, s0);
            s1 = mfma16(aq[ks], b1, s1);
        }
        __builtin_amdgcn_s_setprio(0);

        float a0[4], a1[4];
        float lmax = -1e30f;
        #pragma unroll
        for (int i = 0; i < 4; ++i) {
            a0[i] = s0[i] * scale;
            a1[i] = s1[i] * scale;
            lmax = fmaxf(lmax, fmaxf(a0[i], a1[i]));
        }
        const float mmin = fminf(fminf(mrun[0], mrun[1]), fminf(mrun[2], mrun[3]));
        if (!__all(lmax <= mmin + 8.0f)) {
            // slow path: per-row max reduce, rescale o and lsum
            #pragma unroll
            for (int i = 0; i < 4; ++i) {
                float mx = fmaxf(a0[i], a1[i]);
                mx = fmaxf(mx, __shfl_xor(mx, 1));
                mx = fmaxf(mx, __shfl_xor(mx, 2));
                mx = fmaxf(mx, __shfl_xor(mx, 4));
                mx = fmaxf(mx, __shfl_xor(mx, 8));
                const float mnew = fmaxf(mrun[i], mx);
                const float f = __expf(mrun[i] - mnew);
                mrun[i] = mnew;
                lsum[i] *= f;
                #pragma unroll
                for (int dt = 0; dt < 5; ++dt) o[dt][i] *= f;
            }
        }
        #pragma unroll
        for (int i = 0; i < 4; ++i) {
            float p0 = __expf(a0[i] - mrun[i]);
            float p1 = __expf(a1[i] - mrun[i]);
            lsum[i] += p0 + p1;
            plds[wid][fq * 4 + i][fr]      = f2bf(p0);
            plds[wid][fq * 4 + i][16 + fr] = f2bf(p1);
        }
        // wave-private LDS: compiler's lgkmcnt wait orders write->read; no barrier needed
        short8 pa = *(const short8*)&plds[wid][fr][fq * 8];
        __builtin_amdgcn_s_setprio(1);
        #pragma unroll
        for (int dt = 0; dt < 5; ++dt) {
            short8 bv = *(const short8*)&vh[(size_t)(dt * 16 + fr) * Ntok + kv + fq * 8];
            o[dt] = mfma16(pa, bv, o[dt]);
        }
        __builtin_amdgcn_s_setprio(0);
    }

    float inv[4];
    #pragma unroll
    for (int i = 0; i < 4; ++i) {
        float s = lsum[i];
        s += __shfl_xor(s, 1);
        s += __shfl_xor(s, 2);
        s += __shfl_xor(s, 4);
        s += __shfl_xor(s, 8);
        inv[i] = 1.0f / s;
    }
    const int b = bh >> 4, h = bh & 15;
    #pragma unroll
    for (int dt = 0; dt < 5; ++dt) {
        const int d = dt * 16 + fr;
        if (d < Dh) {
            #pragma unroll
            for (int i = 0; i < 4; ++i) {
                const size_t idx = ((size_t)(b * Ntok) + q0 + fq * 4 + i) * Cdim + h * Dh + d;
                out[idx] = f2bf(o[dt][i] * inv[i]);
            }
        }
    }
}

// ---------------- launch ----------------
extern "C" void kernel_launch(void* const* d_in, const int* in_sizes, int n_in,
                              void* d_out, int out_size, void* d_ws, size_t ws_size,
                              hipStream_t stream) {
    const float* x      = (const float*)d_in[0];
    const float* ln1_g  = (const float*)d_in[1];
    const float* ln1_b  = (const float*)d_in[2];
    const float* qkv_w  = (const float*)d_in[3];
    const float* qkv_b  = (const float*)d_in[4];
    const float* proj_w = (const float*)d_in[5];
    const float* proj_b = (const float*)d_in[6];
    const float* ln2_g  = (const float*)d_in[7];
    const float* ln2_b  = (const float*)d_in[8];
    const float* fc1_w  = (const float*)d_in[9];
    const float* fc1_b  = (const float*)d_in[10];
    const float* fc2_w  = (const float*)d_in[11];
    const float* fc2_b  = (const float*)d_in[12];

    char* ws = (char*)d_ws;
    ushort_t* qkv_wT  = (ushort_t*)(ws + OFF_QKV_WT);
    ushort_t* proj_wT = (ushort_t*)(ws + OFF_PROJ_WT);
    ushort_t* fc1_wT  = (ushort_t*)(ws + OFF_FC1_WT);
    ushort_t* fc2_wT  = (ushort_t*)(ws + OFF_FC2_WT);
    ushort_t* hbuf    = (ushort_t*)(ws + OFF_H);
    ushort_t* attnout = (ushort_t*)(ws + OFF_ATT);
    ushort_t* qb      = (ushort_t*)(ws + OFF_Q);
    ushort_t* kb      = (ushort_t*)(ws + OFF_K);
    ushort_t* vtb     = (ushort_t*)(ws + OFF_VT);
    ushort_t* hidden  = (ushort_t*)(ws + OFF_HIDDEN);
    float* out = (float*)d_out;

    // zero q/k/vt (covers the D=72..95 padding the MFMA K-loop reads)
    hipMemsetAsync(ws + OFF_Q, 0, (size_t)3 * 50331648, stream);

    transpose_cast<<<dim3(3 * Cdim / 64, Cdim / 64), 256, 0, stream>>>(qkv_w, qkv_wT, Cdim, 3 * Cdim);
    transpose_cast<<<dim3(Cdim / 64, Cdim / 64), 256, 0, stream>>>(proj_w, proj_wT, Cdim, Cdim);
    transpose_cast<<<dim3(INNER / 64, Cdim / 64), 256, 0, stream>>>(fc1_w, fc1_wT, Cdim, INNER);
    transpose_cast<<<dim3(Cdim / 64, INNER / 64), 256, 0, stream>>>(fc2_w, fc2_wT, INNER, Cdim);

    ln_kernel<<<Mrows, 256, 0, stream>>>(x, ln1_g, ln1_b, hbuf);

    gemm_bt<EPI_QKV, 3 * Cdim, Cdim><<<dim3(27, 128), 256, 0, stream>>>(
        hbuf, qkv_wT, qkv_b, nullptr, nullptr, nullptr, qb, kb, vtb);

    attn_kernel<<<dim3(Ntok / 64, Bsz * Hn), 256, 0, stream>>>(qb, kb, vtb, attnout);

    gemm_bt<EPI_PROJ, Cdim, Cdim><<<dim3(9, 128), 256, 0, stream>>>(
        attnout, proj_wT, proj_b, x, out, nullptr, nullptr, nullptr, nullptr);

    ln_kernel<<<Mrows, 256, 0, stream>>>(out, ln2_g, ln2_b, hbuf);

    gemm_bt<EPI_FC1, INNER, Cdim><<<dim3(36, 128), 256, 0, stream>>>(
        hbuf, fc1_wT, fc1_b, nullptr, nullptr, hidden, nullptr, nullptr, nullptr);

    gemm_bt<EPI_FC2, Cdim, INNER><<<dim3(9, 128), 256, 0, stream>>>(
        hidden, fc2_wT, fc2_b, nullptr, out, nullptr, nullptr, nullptr, nullptr);
}

// Round 6
// 1233.081 us; speedup vs baseline: 1.2882x; 1.2882x over previous
//
#include <hip/hip_runtime.h>
#include <hip/hip_bf16.h>

typedef unsigned short ushort_t;
using short8 = __attribute__((ext_vector_type(8))) short;
using f32x4  = __attribute__((ext_vector_type(4))) float;

#define DEVI __device__ __forceinline__

DEVI ushort_t f2bf(float f) {
    union { float f; unsigned u; } c; c.f = f;
    unsigned u = c.u;
    return (ushort_t)((u + 0x7FFF + ((u >> 16) & 1)) >> 16);
}

DEVI f32x4 mfma16(short8 a, short8 b, f32x4 c) {
    return __builtin_amdgcn_mfma_f32_16x16x32_bf16(a, b, c, 0, 0, 0);
}

DEVI void gld16(const void* g, void* l) {
    __builtin_amdgcn_global_load_lds(
        (const __attribute__((address_space(1))) unsigned int*)g,
        (__attribute__((address_space(3))) unsigned int*)l, 16, 0, 0);
}

// ---------------- constants ----------------
#define Bsz 16
#define Ntok 1024
#define Cdim 1152
#define Hn 16
#define Dh 72
#define Dp 96
#define INNER 4608
#define Mrows (Bsz * Ntok)   // 16384

// workspace offsets (bytes)
#define OFF_QKV_WT  ((size_t)0)
#define OFF_PROJ_WT ((size_t)7962624)
#define OFF_FC1_WT  ((size_t)10616832)
#define OFF_FC2_WT  ((size_t)21233664)
#define OFF_H       ((size_t)31850496)
#define OFF_ATT     ((size_t)69599232)
#define OFF_Q       ((size_t)107347968)
#define OFF_K       ((size_t)157679616)
#define OFF_VT      ((size_t)208011264)
// hidden (16384x4608 bf16 = 150994944 B) aliases OFF_Q..OFF_VT end (dead by then)
#define OFF_HIDDEN  OFF_Q

// ---------------- weight transpose + cast: W[K][N] f32 -> Wt[N][K] bf16 ----------------
__global__ __launch_bounds__(256) void transpose_cast(
    const float* __restrict__ W, ushort_t* __restrict__ Wt, int K, int N)
{
    __shared__ float t[64][65];
    const int n0 = blockIdx.x * 64;
    const int k0 = blockIdx.y * 64;
    #pragma unroll
    for (int j = 0; j < 4; ++j) {
        int idx = threadIdx.x + j * 256;
        int r = idx >> 4;       // k row 0..63
        int c4 = idx & 15;      // n group of 4
        float4 v = *(const float4*)&W[(size_t)(k0 + r) * N + n0 + c4 * 4];
        t[r][c4 * 4 + 0] = v.x; t[r][c4 * 4 + 1] = v.y;
        t[r][c4 * 4 + 2] = v.z; t[r][c4 * 4 + 3] = v.w;
    }
    __syncthreads();
    #pragma unroll
    for (int j = 0; j < 4; ++j) {
        int idx = threadIdx.x + j * 256;
        int rn = idx >> 4;      // n row 0..63
        int c4 = idx & 15;      // k group of 4
        ushort4 o;
        o.x = f2bf(t[c4 * 4 + 0][rn]);
        o.y = f2bf(t[c4 * 4 + 1][rn]);
        o.z = f2bf(t[c4 * 4 + 2][rn]);
        o.w = f2bf(t[c4 * 4 + 3][rn]);
        *(ushort4*)&Wt[(size_t)(n0 + rn) * K + k0 + c4 * 4] = o;
    }
}

// ---------------- LayerNorm: f32 row(1152) -> bf16 ----------------
__global__ __launch_bounds__(256) void ln_kernel(
    const float* __restrict__ x, const float* __restrict__ g,
    const float* __restrict__ b, ushort_t* __restrict__ out)
{
    const int row = blockIdx.x;
    const int tid = threadIdx.x;
    const int lane = tid & 63, wid = tid >> 6;
    const float* xr = x + (size_t)row * Cdim;

    float4 v0 = ((const float4*)xr)[tid];
    float4 v1 = {0, 0, 0, 0};
    if (tid < 32) v1 = ((const float4*)xr)[256 + tid];
    float s  = v0.x + v0.y + v0.z + v0.w + v1.x + v1.y + v1.z + v1.w;
    float s2 = v0.x*v0.x + v0.y*v0.y + v0.z*v0.z + v0.w*v0.w
             + v1.x*v1.x + v1.y*v1.y + v1.z*v1.z + v1.w*v1.w;
    #pragma unroll
    for (int off = 32; off >= 1; off >>= 1) {
        s  += __shfl_xor(s, off);
        s2 += __shfl_xor(s2, off);
    }
    __shared__ float red[8];
    if (lane == 0) { red[wid] = s; red[4 + wid] = s2; }
    __syncthreads();
    s  = red[0] + red[1] + red[2] + red[3];
    s2 = red[4] + red[5] + red[6] + red[7];
    const float mu = s * (1.0f / Cdim);
    const float var = s2 * (1.0f / Cdim) - mu * mu;
    const float rs = rsqrtf(var + 1e-6f);

    ushort_t* orow = out + (size_t)row * Cdim;
    {
        float4 g4 = ((const float4*)g)[tid];
        float4 b4 = ((const float4*)b)[tid];
        ushort4 o;
        o.x = f2bf((v0.x - mu) * rs * g4.x + b4.x);
        o.y = f2bf((v0.y - mu) * rs * g4.y + b4.y);
        o.z = f2bf((v0.z - mu) * rs * g4.z + b4.z);
        o.w = f2bf((v0.w - mu) * rs * g4.w + b4.w);
        ((ushort4*)orow)[tid] = o;
    }
    if (tid < 32) {
        float4 g4 = ((const float4*)g)[256 + tid];
        float4 b4 = ((const float4*)b)[256 + tid];
        ushort4 o;
        o.x = f2bf((v1.x - mu) * rs * g4.x + b4.x);
        o.y = f2bf((v1.y - mu) * rs * g4.y + b4.y);
        o.z = f2bf((v1.z - mu) * rs * g4.z + b4.z);
        o.w = f2bf((v1.w - mu) * rs * g4.w + b4.w);
        ((ushort4*)orow)[256 + tid] = o;
    }
}

// ---------------- GEMM: C[M,N] = A[M,K](bf16) @ Bt[N,K]^T(bf16), epilogues ----------------
// (Round-1 exact structure: no swizzle, no setprio — clean A/B vs attn change)
enum { EPI_QKV = 0, EPI_PROJ = 1, EPI_FC1 = 2, EPI_FC2 = 3 };

template<int EPI, int N, int K>
__global__ __launch_bounds__(256) void gemm_bt(
    const ushort_t* __restrict__ A, const ushort_t* __restrict__ Bt,
    const float* __restrict__ bias, const float* __restrict__ resid,
    float* __restrict__ outf, ushort_t* __restrict__ outb,
    ushort_t* __restrict__ outq, ushort_t* __restrict__ outk, ushort_t* __restrict__ outv)
{
    __shared__ ushort_t As[128 * 32];
    __shared__ ushort_t Bs[128 * 32];
    const int tid = threadIdx.x;
    const int lane = tid & 63, wid = tid >> 6;
    const int m0 = blockIdx.y * 128;
    const int n0 = blockIdx.x * 128;
    const int fr = lane & 15, fq = lane >> 4;

    f32x4 acc[4][4] = {};

    const int srow = lane >> 2;          // 0..15 within 16-row chunk
    const int scol = (lane & 3) * 8;     // k element offset within 32
    const ushort_t* Ag = A + (size_t)m0 * K;
    const ushort_t* Bg = Bt + (size_t)n0 * K;

    for (int kk = 0; kk < K; kk += 32) {
        #pragma unroll
        for (int j = 0; j < 2; ++j) {
            const int crow = wid * 32 + j * 16;          // chunk base row
            gld16(Ag + (size_t)(crow + srow) * K + kk + scol, &As[crow * 32]);
            gld16(Bg + (size_t)(crow + srow) * K + kk + scol, &Bs[crow * 32]);
        }
        __syncthreads();
        short8 af[4], bfr[4];
        #pragma unroll
        for (int mi = 0; mi < 4; ++mi)
            af[mi] = *(const short8*)&As[((wid >> 1) * 64 + mi * 16 + fr) * 32 + fq * 8];
        #pragma unroll
        for (int ni = 0; ni < 4; ++ni)
            bfr[ni] = *(const short8*)&Bs[((wid & 1) * 64 + ni * 16 + fr) * 32 + fq * 8];
        #pragma unroll
        for (int mi = 0; mi < 4; ++mi)
            #pragma unroll
            for (int ni = 0; ni < 4; ++ni)
                acc[mi][ni] = mfma16(af[mi], bfr[ni], acc[mi][ni]);
        __syncthreads();
    }

    #pragma unroll
    for (int mi = 0; mi < 4; ++mi) {
        #pragma unroll
        for (int ni = 0; ni < 4; ++ni) {
            const int col = n0 + (wid & 1) * 64 + ni * 16 + fr;
            const int rbase = m0 + (wid >> 1) * 64 + mi * 16 + fq * 4;
            #pragma unroll
            for (int i = 0; i < 4; ++i) {
                const int r = rbase + i;
                float v = acc[mi][ni][i];
                if (EPI == EPI_QKV) {
                    v += bias[col];
                    const int which = col / Cdim;
                    const int rc = col % Cdim;
                    const int h = rc / Dh, d = rc % Dh;
                    const int b = r >> 10, n = r & 1023;
                    const size_t head = (size_t)(b * Hn + h);
                    if (which == 0)      outq[(head * Ntok + n) * Dp + d] = f2bf(v);
                    else if (which == 1) outk[(head * Ntok + n) * Dp + d] = f2bf(v);
                    else                 outv[(head * Dp + d) * Ntok + n] = f2bf(v);
                } else if (EPI == EPI_PROJ) {
                    v += bias[col] + resid[(size_t)r * N + col];
                    outf[(size_t)r * N + col] = v;
                } else if (EPI == EPI_FC1) {
                    v += bias[col];
                    v = 0.5f * v * (1.0f + erff(v * 0.70710678118f));
                    outb[(size_t)r * N + col] = f2bf(v);
                } else { // EPI_FC2
                    v += bias[col] + outf[(size_t)r * N + col];
                    outf[(size_t)r * N + col] = v;
                }
            }
        }
    }
}

// ---------------- flash attention: q,k (bh,n,96) bf16; vt (bh,96,n); out (b,n,1152) bf16 ----
// 2 q-tiles per wave (32 q-rows): K/V loads amortized over 2x MFMA work, two
// independent accumulator chains for ILP. All 11 global loads issued at the top
// of each KV iteration so their latency overlaps QK+softmax. Barrier-free.
__global__ __launch_bounds__(256) void attn_kernel(
    const ushort_t* __restrict__ q, const ushort_t* __restrict__ k,
    const ushort_t* __restrict__ vt, ushort_t* __restrict__ out)
{
    const int tid = threadIdx.x;
    const int lane = tid & 63, wid = tid >> 6;
    const int bh = blockIdx.y;
    const int qbase = blockIdx.x * 128 + wid * 32;
    const int fr = lane & 15, fq = lane >> 4;
    const ushort_t* qh = q  + (size_t)bh * Ntok * Dp;
    const ushort_t* kh = k  + (size_t)bh * Ntok * Dp;
    const ushort_t* vh = vt + (size_t)bh * Dp * Ntok;

    short8 aq[2][3];
    #pragma unroll
    for (int t = 0; t < 2; ++t)
        #pragma unroll
        for (int ks = 0; ks < 3; ++ks)
            aq[t][ks] = *(const short8*)&qh[(size_t)(qbase + t * 16 + fr) * Dp + ks * 32 + fq * 8];

    f32x4 o[2][5] = {};
    float mrun[2][4], lsum[2][4];
    #pragma unroll
    for (int t = 0; t < 2; ++t)
        #pragma unroll
        for (int i = 0; i < 4; ++i) { mrun[t][i] = -1e30f; lsum[t][i] = 0.0f; }

    __shared__ ushort_t plds[4][2][16][32];
    const float scale = 0.117851130f;   // 72^-0.5

    for (int kv = 0; kv < Ntok; kv += 32) {
        // issue ALL global loads for this iteration up front (K tiles + V tiles)
        short8 kb0[3], kb1[3], bv[5];
        #pragma unroll
        for (int ks = 0; ks < 3; ++ks) {
            kb0[ks] = *(const short8*)&kh[(size_t)(kv + fr) * Dp + ks * 32 + fq * 8];
            kb1[ks] = *(const short8*)&kh[(size_t)(kv + 16 + fr) * Dp + ks * 32 + fq * 8];
        }
        #pragma unroll
        for (int dt = 0; dt < 5; ++dt)
            bv[dt] = *(const short8*)&vh[(size_t)(dt * 16 + fr) * Ntok + kv + fq * 8];

        f32x4 s[2][2] = {};
        __builtin_amdgcn_s_setprio(1);
        #pragma unroll
        for (int ks = 0; ks < 3; ++ks)
            #pragma unroll
            for (int t = 0; t < 2; ++t) {
                s[t][0] = mfma16(aq[t][ks], kb0[ks], s[t][0]);
                s[t][1] = mfma16(aq[t][ks], kb1[ks], s[t][1]);
            }
        __builtin_amdgcn_s_setprio(0);

        #pragma unroll
        for (int t = 0; t < 2; ++t) {
            float a0[4], a1[4];
            float lmax = -1e30f;
            #pragma unroll
            for (int i = 0; i < 4; ++i) {
                a0[i] = s[t][0][i] * scale;
                a1[i] = s[t][1][i] * scale;
                lmax = fmaxf(lmax, fmaxf(a0[i], a1[i]));
            }
            const float mmin = fminf(fminf(mrun[t][0], mrun[t][1]),
                                     fminf(mrun[t][2], mrun[t][3]));
            if (!__all(lmax <= mmin + 8.0f)) {
                #pragma unroll
                for (int i = 0; i < 4; ++i) {
                    float mx = fmaxf(a0[i], a1[i]);
                    mx = fmaxf(mx, __shfl_xor(mx, 1));
                    mx = fmaxf(mx, __shfl_xor(mx, 2));
                    mx = fmaxf(mx, __shfl_xor(mx, 4));
                    mx = fmaxf(mx, __shfl_xor(mx, 8));
                    const float mnew = fmaxf(mrun[t][i], mx);
                    const float f = __expf(mrun[t][i] - mnew);
                    mrun[t][i] = mnew;
                    lsum[t][i] *= f;
                    #pragma unroll
                    for (int dt = 0; dt < 5; ++dt) o[t][dt][i] *= f;
                }
            }
            #pragma unroll
            for (int i = 0; i < 4; ++i) {
                float p0 = __expf(a0[i] - mrun[t][i]);
                float p1 = __expf(a1[i] - mrun[t][i]);
                lsum[t][i] += p0 + p1;
                plds[wid][t][fq * 4 + i][fr]      = f2bf(p0);
                plds[wid][t][fq * 4 + i][16 + fr] = f2bf(p1);
            }
        }
        // wave-private LDS bounce: compiler's lgkmcnt wait orders write->read
        short8 pa[2];
        #pragma unroll
        for (int t = 0; t < 2; ++t)
            pa[t] = *(const short8*)&plds[wid][t][fr][fq * 8];
        __builtin_amdgcn_s_setprio(1);
        #pragma unroll
        for (int dt = 0; dt < 5; ++dt)
            #pragma unroll
            for (int t = 0; t < 2; ++t)
                o[t][dt] = mfma16(pa[t], bv[dt], o[t][dt]);
        __builtin_amdgcn_s_setprio(0);
    }

    const int b = bh >> 4, h = bh & 15;
    #pragma unroll
    for (int t = 0; t < 2; ++t) {
        float inv[4];
        #pragma unroll
        for (int i = 0; i < 4; ++i) {
            float s = lsum[t][i];
            s += __shfl_xor(s, 1);
            s += __shfl_xor(s, 2);
            s += __shfl_xor(s, 4);
            s += __shfl_xor(s, 8);
            inv[i] = 1.0f / s;
        }
        #pragma unroll
        for (int dt = 0; dt < 5; ++dt) {
            const int d = dt * 16 + fr;
            if (d < Dh) {
                #pragma unroll
                for (int i = 0; i < 4; ++i) {
                    const size_t idx = ((size_t)(b * Ntok) + qbase + t * 16 + fq * 4 + i) * Cdim + h * Dh + d;
                    out[idx] = f2bf(o[t][dt][i] * inv[i]);
                }
            }
        }
    }
}

// ---------------- launch ----------------
extern "C" void kernel_launch(void* const* d_in, const int* in_sizes, int n_in,
                              void* d_out, int out_size, void* d_ws, size_t ws_size,
                              hipStream_t stream) {
    const float* x      = (const float*)d_in[0];
    const float* ln1_g  = (const float*)d_in[1];
    const float* ln1_b  = (const float*)d_in[2];
    const float* qkv_w  = (const float*)d_in[3];
    const float* qkv_b  = (const float*)d_in[4];
    const float* proj_w = (const float*)d_in[5];
    const float* proj_b = (const float*)d_in[6];
    const float* ln2_g  = (const float*)d_in[7];
    const float* ln2_b  = (const float*)d_in[8];
    const float* fc1_w  = (const float*)d_in[9];
    const float* fc1_b  = (const float*)d_in[10];
    const float* fc2_w  = (const float*)d_in[11];
    const float* fc2_b  = (const float*)d_in[12];

    char* ws = (char*)d_ws;
    ushort_t* qkv_wT  = (ushort_t*)(ws + OFF_QKV_WT);
    ushort_t* proj_wT = (ushort_t*)(ws + OFF_PROJ_WT);
    ushort_t* fc1_wT  = (ushort_t*)(ws + OFF_FC1_WT);
    ushort_t* fc2_wT  = (ushort_t*)(ws + OFF_FC2_WT);
    ushort_t* hbuf    = (ushort_t*)(ws + OFF_H);
    ushort_t* attnout = (ushort_t*)(ws + OFF_ATT);
    ushort_t* qb      = (ushort_t*)(ws + OFF_Q);
    ushort_t* kb      = (ushort_t*)(ws + OFF_K);
    ushort_t* vtb     = (ushort_t*)(ws + OFF_VT);
    ushort_t* hidden  = (ushort_t*)(ws + OFF_HIDDEN);
    float* out = (float*)d_out;

    // zero q/k/vt (covers the D=72..95 padding the MFMA K-loop reads)
    hipMemsetAsync(ws + OFF_Q, 0, (size_t)3 * 50331648, stream);

    transpose_cast<<<dim3(3 * Cdim / 64, Cdim / 64), 256, 0, stream>>>(qkv_w, qkv_wT, Cdim, 3 * Cdim);
    transpose_cast<<<dim3(Cdim / 64, Cdim / 64), 256, 0, stream>>>(proj_w, proj_wT, Cdim, Cdim);
    transpose_cast<<<dim3(INNER / 64, Cdim / 64), 256, 0, stream>>>(fc1_w, fc1_wT, Cdim, INNER);
    transpose_cast<<<dim3(Cdim / 64, INNER / 64), 256, 0, stream>>>(fc2_w, fc2_wT, INNER, Cdim);

    ln_kernel<<<Mrows, 256, 0, stream>>>(x, ln1_g, ln1_b, hbuf);

    gemm_bt<EPI_QKV, 3 * Cdim, Cdim><<<dim3(27, 128), 256, 0, stream>>>(
        hbuf, qkv_wT, qkv_b, nullptr, nullptr, nullptr, qb, kb, vtb);

    attn_kernel<<<dim3(Ntok / 128, Bsz * Hn), 256, 0, stream>>>(qb, kb, vtb, attnout);

    gemm_bt<EPI_PROJ, Cdim, Cdim><<<dim3(9, 128), 256, 0, stream>>>(
        attnout, proj_wT, proj_b, x, out, nullptr, nullptr, nullptr, nullptr);

    ln_kernel<<<Mrows, 256, 0, stream>>>(out, ln2_g, ln2_b, hbuf);

    gemm_bt<EPI_FC1, INNER, Cdim><<<dim3(36, 128), 256, 0, stream>>>(
        hbuf, fc1_wT, fc1_b, nullptr, nullptr, hidden, nullptr, nullptr, nullptr);

    gemm_bt<EPI_FC2, Cdim, INNER><<<dim3(9, 128), 256, 0, stream>>>(
        hidden, fc2_wT, fc2_b, nullptr, out, nullptr, nullptr, nullptr, nullptr);
}

// Round 7
// 1133.131 us; speedup vs baseline: 1.4018x; 1.0882x over previous
//
#include <hip/hip_runtime.h>
#include <hip/hip_bf16.h>

typedef unsigned short ushort_t;
using short8 = __attribute__((ext_vector_type(8))) short;
using f32x4  = __attribute__((ext_vector_type(4))) float;

#define DEVI __device__ __forceinline__

DEVI ushort_t f2bf(float f) {
    union { float f; unsigned u; } c; c.f = f;
    unsigned u = c.u;
    return (ushort_t)((u + 0x7FFF + ((u >> 16) & 1)) >> 16);
}

DEVI f32x4 mfma16(short8 a, short8 b, f32x4 c) {
    return __builtin_amdgcn_mfma_f32_16x16x32_bf16(a, b, c, 0, 0, 0);
}

DEVI void gld16(const void* g, void* l) {
    __builtin_amdgcn_global_load_lds(
        (const __attribute__((address_space(1))) unsigned int*)g,
        (__attribute__((address_space(3))) unsigned int*)l, 16, 0, 0);
}

// ---------------- constants ----------------
#define Bsz 16
#define Ntok 1024
#define Cdim 1152
#define Hn 16
#define Dh 72
#define Dp 96
#define INNER 4608
#define Mrows (Bsz * Ntok)   // 16384

// workspace offsets (bytes)
#define OFF_QKV_WT  ((size_t)0)
#define OFF_PROJ_WT ((size_t)7962624)
#define OFF_FC1_WT  ((size_t)10616832)
#define OFF_FC2_WT  ((size_t)21233664)
#define OFF_H       ((size_t)31850496)
#define OFF_ATT     ((size_t)69599232)
#define OFF_Q       ((size_t)107347968)
#define OFF_K       ((size_t)157679616)
#define OFF_VT      ((size_t)208011264)
#define OFF_HIDDEN  OFF_Q

// ---------------- weight transpose + cast: W[K][N] f32 -> Wt[N][K] bf16 ----------------
__global__ __launch_bounds__(256) void transpose_cast(
    const float* __restrict__ W, ushort_t* __restrict__ Wt, int K, int N)
{
    __shared__ float t[64][65];
    const int n0 = blockIdx.x * 64;
    const int k0 = blockIdx.y * 64;
    #pragma unroll
    for (int j = 0; j < 4; ++j) {
        int idx = threadIdx.x + j * 256;
        int r = idx >> 4;
        int c4 = idx & 15;
        float4 v = *(const float4*)&W[(size_t)(k0 + r) * N + n0 + c4 * 4];
        t[r][c4 * 4 + 0] = v.x; t[r][c4 * 4 + 1] = v.y;
        t[r][c4 * 4 + 2] = v.z; t[r][c4 * 4 + 3] = v.w;
    }
    __syncthreads();
    #pragma unroll
    for (int j = 0; j < 4; ++j) {
        int idx = threadIdx.x + j * 256;
        int rn = idx >> 4;
        int c4 = idx & 15;
        ushort4 o;
        o.x = f2bf(t[c4 * 4 + 0][rn]);
        o.y = f2bf(t[c4 * 4 + 1][rn]);
        o.z = f2bf(t[c4 * 4 + 2][rn]);
        o.w = f2bf(t[c4 * 4 + 3][rn]);
        *(ushort4*)&Wt[(size_t)(n0 + rn) * K + k0 + c4 * 4] = o;
    }
}

// ---------------- LayerNorm: f32 row(1152) -> bf16 ----------------
__global__ __launch_bounds__(256) void ln_kernel(
    const float* __restrict__ x, const float* __restrict__ g,
    const float* __restrict__ b, ushort_t* __restrict__ out)
{
    const int row = blockIdx.x;
    const int tid = threadIdx.x;
    const int lane = tid & 63, wid = tid >> 6;
    const float* xr = x + (size_t)row * Cdim;

    float4 v0 = ((const float4*)xr)[tid];
    float4 v1 = {0, 0, 0, 0};
    if (tid < 32) v1 = ((const float4*)xr)[256 + tid];
    float s  = v0.x + v0.y + v0.z + v0.w + v1.x + v1.y + v1.z + v1.w;
    float s2 = v0.x*v0.x + v0.y*v0.y + v0.z*v0.z + v0.w*v0.w
             + v1.x*v1.x + v1.y*v1.y + v1.z*v1.z + v1.w*v1.w;
    #pragma unroll
    for (int off = 32; off >= 1; off >>= 1) {
        s  += __shfl_xor(s, off);
        s2 += __shfl_xor(s2, off);
    }
    __shared__ float red[8];
    if (lane == 0) { red[wid] = s; red[4 + wid] = s2; }
    __syncthreads();
    s  = red[0] + red[1] + red[2] + red[3];
    s2 = red[4] + red[5] + red[6] + red[7];
    const float mu = s * (1.0f / Cdim);
    const float var = s2 * (1.0f / Cdim) - mu * mu;
    const float rs = rsqrtf(var + 1e-6f);

    ushort_t* orow = out + (size_t)row * Cdim;
    {
        float4 g4 = ((const float4*)g)[tid];
        float4 b4 = ((const float4*)b)[tid];
        ushort4 o;
        o.x = f2bf((v0.x - mu) * rs * g4.x + b4.x);
        o.y = f2bf((v0.y - mu) * rs * g4.y + b4.y);
        o.z = f2bf((v0.z - mu) * rs * g4.z + b4.z);
        o.w = f2bf((v0.w - mu) * rs * g4.w + b4.w);
        ((ushort4*)orow)[tid] = o;
    }
    if (tid < 32) {
        float4 g4 = ((const float4*)g)[256 + tid];
        float4 b4 = ((const float4*)b)[256 + tid];
        ushort4 o;
        o.x = f2bf((v1.x - mu) * rs * g4.x + b4.x);
        o.y = f2bf((v1.y - mu) * rs * g4.y + b4.y);
        o.z = f2bf((v1.z - mu) * rs * g4.z + b4.z);
        o.w = f2bf((v1.w - mu) * rs * g4.w + b4.w);
        ((ushort4*)orow)[256 + tid] = o;
    }
}

// ---------------- GEMM: 256x128 tile, BK=64, ring-3 LDS, counted vmcnt ----------------
// 512 threads = 8 waves (4M x 2N), per-wave 64x64 output (acc[4][4] of 16x16).
// LDS per buffer: A 256x64 + B 128x64 bf16 = 48 KB; ring of 3 = 144 KB (1 block/CU).
// K-step loop: { vmcnt(6); s_barrier; stage(t+2); ds_read+MFMA (2 half-K phases) }.
// Loads stay in flight across barriers (T4). LDS XOR-swizzle (T2): read byte
// ^= (row&7)<<4; global source pre-permuted so gld16's linear dest matches.
enum { EPI_QKV = 0, EPI_PROJ = 1, EPI_FC1 = 2, EPI_FC2 = 3 };

#define TBM 256
#define TBN 128
#define TBK 64
#define BUFB 49152   // bytes per ring buffer (A 32768 + B 16384)

template<int EPI, int N, int K>
__global__ __launch_bounds__(512, 2) void gemm_bt(
    const ushort_t* __restrict__ A, const ushort_t* __restrict__ Bt,
    const float* __restrict__ bias, const float* __restrict__ resid,
    float* __restrict__ outf, ushort_t* __restrict__ outb,
    ushort_t* __restrict__ outq, ushort_t* __restrict__ outk, ushort_t* __restrict__ outv)
{
    __shared__ ushort_t smem[3 * BUFB / 2];
    const int tid = threadIdx.x;
    const int lane = tid & 63, wid = tid >> 6;
    const int wr = wid >> 1, wc = wid & 1;
    const int fr = lane & 15, fq = lane >> 4;
    const int m0 = blockIdx.y * TBM;
    const int n0 = blockIdx.x * TBN;

    const ushort_t* Ag = A + (size_t)m0 * K;
    const ushort_t* Bg = Bt + (size_t)n0 * K;

    // staging: round r covers chunks r*512+tid; chunk -> (row, slot); source col
    // is slot^(row&7) so that linear LDS + swizzled read round-trips.
    size_t srcA[4]; int dstA[4];
    #pragma unroll
    for (int r = 0; r < 4; ++r) {
        const int chunk = r * 512 + tid;
        const int row = chunk >> 3;
        const int slot = chunk & 7;
        srcA[r] = (size_t)row * K + (slot ^ (row & 7)) * 8;
        dstA[r] = (r * 512 + wid * 64) * 16;             // + lane*16 by HW
    }
    size_t srcB[2]; int dstB[2];
    #pragma unroll
    for (int r = 0; r < 2; ++r) {
        const int chunk = r * 512 + tid;
        const int row = chunk >> 3;
        const int slot = chunk & 7;
        srcB[r] = (size_t)row * K + (slot ^ (row & 7)) * 8;
        dstB[r] = 32768 + (r * 512 + wid * 64) * 16;
    }

    auto STAGE = [&](int buf, int kk) {
        char* lb = (char*)smem + (size_t)buf * BUFB;
        #pragma unroll
        for (int r = 0; r < 4; ++r) gld16(Ag + srcA[r] + kk, lb + dstA[r]);
        #pragma unroll
        for (int r = 0; r < 2; ++r) gld16(Bg + srcB[r] + kk, lb + dstB[r]);
    };

    // fragment read offsets (bytes within buffer), swizzled
    const int swz = (fr & 7) << 4;
    int aoff[4][2], boff[4][2];
    #pragma unroll
    for (int i = 0; i < 4; ++i)
        #pragma unroll
        for (int kh = 0; kh < 2; ++kh) {
            const int rowA = wr * 64 + i * 16 + fr;
            aoff[i][kh] = rowA * 128 + ((kh * 64 + fq * 16) ^ swz);
            const int rowB = wc * 64 + i * 16 + fr;
            boff[i][kh] = 32768 + rowB * 128 + ((kh * 64 + fq * 16) ^ swz);
        }

    f32x4 acc[4][4] = {};
    const int NT = K / TBK;

    STAGE(0, 0);
    STAGE(1, TBK);

    auto COMPUTE = [&](int t) {
        const char* lb = (const char*)smem + (size_t)(t % 3) * BUFB;
        #pragma unroll
        for (int kh = 0; kh < 2; ++kh) {
            short8 a[4], b[4];
            #pragma unroll
            for (int i = 0; i < 4; ++i) {
                a[i] = *(const short8*)(lb + aoff[i][kh]);
                b[i] = *(const short8*)(lb + boff[i][kh]);
            }
            __builtin_amdgcn_s_setprio(1);
            #pragma unroll
            for (int mi = 0; mi < 4; ++mi)
                #pragma unroll
                for (int ni = 0; ni < 4; ++ni)
                    acc[mi][ni] = mfma16(a[mi], b[ni], acc[mi][ni]);
            __builtin_amdgcn_s_setprio(0);
        }
    };

    for (int t = 0; t < NT - 1; ++t) {
        asm volatile("s_waitcnt vmcnt(6)" ::: "memory");
        __builtin_amdgcn_s_barrier();
        __builtin_amdgcn_sched_barrier(0);
        if (t + 2 < NT) STAGE((t + 2) % 3, (t + 2) * TBK);
        __builtin_amdgcn_sched_barrier(0);
        COMPUTE(t);
    }
    asm volatile("s_waitcnt vmcnt(0)" ::: "memory");
    __builtin_amdgcn_s_barrier();
    __builtin_amdgcn_sched_barrier(0);
    COMPUTE(NT - 1);

    // ---------------- epilogue ----------------
    #pragma unroll
    for (int mi = 0; mi < 4; ++mi) {
        #pragma unroll
        for (int ni = 0; ni < 4; ++ni) {
            const int col = n0 + wc * 64 + ni * 16 + fr;
            const int rbase = m0 + wr * 64 + mi * 16 + fq * 4;
            #pragma unroll
            for (int i = 0; i < 4; ++i) {
                const int r = rbase + i;
                float v = acc[mi][ni][i];
                if (EPI == EPI_QKV) {
                    v += bias[col];
                    const int which = col / Cdim;
                    const int rc = col % Cdim;
                    const int h = rc / Dh, d = rc % Dh;
                    const int b = r >> 10, n = r & 1023;
                    const size_t head = (size_t)(b * Hn + h);
                    if (which == 0)      outq[(head * Ntok + n) * Dp + d] = f2bf(v);
                    else if (which == 1) outk[(head * Ntok + n) * Dp + d] = f2bf(v);
                    else                 outv[(head * Dp + d) * Ntok + n] = f2bf(v);
                } else if (EPI == EPI_PROJ) {
                    v += bias[col] + resid[(size_t)r * N + col];
                    outf[(size_t)r * N + col] = v;
                } else if (EPI == EPI_FC1) {
                    v += bias[col];
                    v = 0.5f * v * (1.0f + erff(v * 0.70710678118f));
                    outb[(size_t)r * N + col] = f2bf(v);
                } else { // EPI_FC2
                    v += bias[col] + outf[(size_t)r * N + col];
                    outf[(size_t)r * N + col] = v;
                }
            }
        }
    }
}

// ---------------- flash attention (unchanged from round 6) ----------------
__global__ __launch_bounds__(256) void attn_kernel(
    const ushort_t* __restrict__ q, const ushort_t* __restrict__ k,
    const ushort_t* __restrict__ vt, ushort_t* __restrict__ out)
{
    const int tid = threadIdx.x;
    const int lane = tid & 63, wid = tid >> 6;
    const int bh = blockIdx.y;
    const int qbase = blockIdx.x * 128 + wid * 32;
    const int fr = lane & 15, fq = lane >> 4;
    const ushort_t* qh = q  + (size_t)bh * Ntok * Dp;
    const ushort_t* kh = k  + (size_t)bh * Ntok * Dp;
    const ushort_t* vh = vt + (size_t)bh * Dp * Ntok;

    short8 aq[2][3];
    #pragma unroll
    for (int t = 0; t < 2; ++t)
        #pragma unroll
        for (int ks = 0; ks < 3; ++ks)
            aq[t][ks] = *(const short8*)&qh[(size_t)(qbase + t * 16 + fr) * Dp + ks * 32 + fq * 8];

    f32x4 o[2][5] = {};
    float mrun[2][4], lsum[2][4];
    #pragma unroll
    for (int t = 0; t < 2; ++t)
        #pragma unroll
        for (int i = 0; i < 4; ++i) { mrun[t][i] = -1e30f; lsum[t][i] = 0.0f; }

    __shared__ ushort_t plds[4][2][16][32];
    const float scale = 0.117851130f;   // 72^-0.5

    for (int kv = 0; kv < Ntok; kv += 32) {
        short8 kb0[3], kb1[3], bv[5];
        #pragma unroll
        for (int ks = 0; ks < 3; ++ks) {
            kb0[ks] = *(const short8*)&kh[(size_t)(kv + fr) * Dp + ks * 32 + fq * 8];
            kb1[ks] = *(const short8*)&kh[(size_t)(kv + 16 + fr) * Dp + ks * 32 + fq * 8];
        }
        #pragma unroll
        for (int dt = 0; dt < 5; ++dt)
            bv[dt] = *(const short8*)&vh[(size_t)(dt * 16 + fr) * Ntok + kv + fq * 8];

        f32x4 s[2][2] = {};
        __builtin_amdgcn_s_setprio(1);
        #pragma unroll
        for (int ks = 0; ks < 3; ++ks)
            #pragma unroll
            for (int t = 0; t < 2; ++t) {
                s[t][0] = mfma16(aq[t][ks], kb0[ks], s[t][0]);
                s[t][1] = mfma16(aq[t][ks], kb1[ks], s[t][1]);
            }
        __builtin_amdgcn_s_setprio(0);

        #pragma unroll
        for (int t = 0; t < 2; ++t) {
            float a0[4], a1[4];
            float lmax = -1e30f;
            #pragma unroll
            for (int i = 0; i < 4; ++i) {
                a0[i] = s[t][0][i] * scale;
                a1[i] = s[t][1][i] * scale;
                lmax = fmaxf(lmax, fmaxf(a0[i], a1[i]));
            }
            const float mmin = fminf(fminf(mrun[t][0], mrun[t][1]),
                                     fminf(mrun[t][2], mrun[t][3]));
            if (!__all(lmax <= mmin + 8.0f)) {
                #pragma unroll
                for (int i = 0; i < 4; ++i) {
                    float mx = fmaxf(a0[i], a1[i]);
                    mx = fmaxf(mx, __shfl_xor(mx, 1));
                    mx = fmaxf(mx, __shfl_xor(mx, 2));
                    mx = fmaxf(mx, __shfl_xor(mx, 4));
                    mx = fmaxf(mx, __shfl_xor(mx, 8));
                    const float mnew = fmaxf(mrun[t][i], mx);
                    const float f = __expf(mrun[t][i] - mnew);
                    mrun[t][i] = mnew;
                    lsum[t][i] *= f;
                    #pragma unroll
                    for (int dt = 0; dt < 5; ++dt) o[t][dt][i] *= f;
                }
            }
            #pragma unroll
            for (int i = 0; i < 4; ++i) {
                float p0 = __expf(a0[i] - mrun[t][i]);
                float p1 = __expf(a1[i] - mrun[t][i]);
                lsum[t][i] += p0 + p1;
                plds[wid][t][fq * 4 + i][fr]      = f2bf(p0);
                plds[wid][t][fq * 4 + i][16 + fr] = f2bf(p1);
            }
        }
        short8 pa[2];
        #pragma unroll
        for (int t = 0; t < 2; ++t)
            pa[t] = *(const short8*)&plds[wid][t][fr][fq * 8];
        __builtin_amdgcn_s_setprio(1);
        #pragma unroll
        for (int dt = 0; dt < 5; ++dt)
            #pragma unroll
            for (int t = 0; t < 2; ++t)
                o[t][dt] = mfma16(pa[t], bv[dt], o[t][dt]);
        __builtin_amdgcn_s_setprio(0);
    }

    const int b = bh >> 4, h = bh & 15;
    #pragma unroll
    for (int t = 0; t < 2; ++t) {
        float inv[4];
        #pragma unroll
        for (int i = 0; i < 4; ++i) {
            float s = lsum[t][i];
            s += __shfl_xor(s, 1);
            s += __shfl_xor(s, 2);
            s += __shfl_xor(s, 4);
            s += __shfl_xor(s, 8);
            inv[i] = 1.0f / s;
        }
        #pragma unroll
        for (int dt = 0; dt < 5; ++dt) {
            const int d = dt * 16 + fr;
            if (d < Dh) {
                #pragma unroll
                for (int i = 0; i < 4; ++i) {
                    const size_t idx = ((size_t)(b * Ntok) + qbase + t * 16 + fq * 4 + i) * Cdim + h * Dh + d;
                    out[idx] = f2bf(o[t][dt][i] * inv[i]);
                }
            }
        }
    }
}

// ---------------- launch ----------------
extern "C" void kernel_launch(void* const* d_in, const int* in_sizes, int n_in,
                              void* d_out, int out_size, void* d_ws, size_t ws_size,
                              hipStream_t stream) {
    const float* x      = (const float*)d_in[0];
    const float* ln1_g  = (const float*)d_in[1];
    const float* ln1_b  = (const float*)d_in[2];
    const float* qkv_w  = (const float*)d_in[3];
    const float* qkv_b  = (const float*)d_in[4];
    const float* proj_w = (const float*)d_in[5];
    const float* proj_b = (const float*)d_in[6];
    const float* ln2_g  = (const float*)d_in[7];
    const float* ln2_b  = (const float*)d_in[8];
    const float* fc1_w  = (const float*)d_in[9];
    const float* fc1_b  = (const float*)d_in[10];
    const float* fc2_w  = (const float*)d_in[11];
    const float* fc2_b  = (const float*)d_in[12];

    char* ws = (char*)d_ws;
    ushort_t* qkv_wT  = (ushort_t*)(ws + OFF_QKV_WT);
    ushort_t* proj_wT = (ushort_t*)(ws + OFF_PROJ_WT);
    ushort_t* fc1_wT  = (ushort_t*)(ws + OFF_FC1_WT);
    ushort_t* fc2_wT  = (ushort_t*)(ws + OFF_FC2_WT);
    ushort_t* hbuf    = (ushort_t*)(ws + OFF_H);
    ushort_t* attnout = (ushort_t*)(ws + OFF_ATT);
    ushort_t* qb      = (ushort_t*)(ws + OFF_Q);
    ushort_t* kb      = (ushort_t*)(ws + OFF_K);
    ushort_t* vtb     = (ushort_t*)(ws + OFF_VT);
    ushort_t* hidden  = (ushort_t*)(ws + OFF_HIDDEN);
    float* out = (float*)d_out;

    // zero q/k/vt (covers the D=72..95 padding the MFMA K-loop reads)
    hipMemsetAsync(ws + OFF_Q, 0, (size_t)3 * 50331648, stream);

    transpose_cast<<<dim3(3 * Cdim / 64, Cdim / 64), 256, 0, stream>>>(qkv_w, qkv_wT, Cdim, 3 * Cdim);
    transpose_cast<<<dim3(Cdim / 64, Cdim / 64), 256, 0, stream>>>(proj_w, proj_wT, Cdim, Cdim);
    transpose_cast<<<dim3(INNER / 64, Cdim / 64), 256, 0, stream>>>(fc1_w, fc1_wT, Cdim, INNER);
    transpose_cast<<<dim3(Cdim / 64, INNER / 64), 256, 0, stream>>>(fc2_w, fc2_wT, INNER, Cdim);

    ln_kernel<<<Mrows, 256, 0, stream>>>(x, ln1_g, ln1_b, hbuf);

    gemm_bt<EPI_QKV, 3 * Cdim, Cdim><<<dim3(27, Mrows / TBM), 512, 0, stream>>>(
        hbuf, qkv_wT, qkv_b, nullptr, nullptr, nullptr, qb, kb, vtb);

    attn_kernel<<<dim3(Ntok / 128, Bsz * Hn), 256, 0, stream>>>(qb, kb, vtb, attnout);

    gemm_bt<EPI_PROJ, Cdim, Cdim><<<dim3(9, Mrows / TBM), 512, 0, stream>>>(
        attnout, proj_wT, proj_b, x, out, nullptr, nullptr, nullptr, nullptr);

    ln_kernel<<<Mrows, 256, 0, stream>>>(out, ln2_g, ln2_b, hbuf);

    gemm_bt<EPI_FC1, INNER, Cdim><<<dim3(36, Mrows / TBM), 512, 0, stream>>>(
        hbuf, fc1_wT, fc1_b, nullptr, nullptr, hidden, nullptr, nullptr, nullptr);

    gemm_bt<EPI_FC2, Cdim, INNER><<<dim3(9, Mrows / TBM), 512, 0, stream>>>(
        hidden, fc2_wT, fc2_b, nullptr, out, nullptr, nullptr, nullptr, nullptr);
}